// Round 1
// baseline (450.443 us; speedup 1.0000x reference)
//
#include <hip/hip_runtime.h>
#include <stdint.h>

// ---------------------------------------------------------------------------
// LSH layer: out[n,s] = sum_d x[n,d] * W[ids[s],d] + bias[ids[s]]
// R3: GEMM upgraded from 128-square single-buffered 2-barrier (m97-class,
//     vmcnt(0) drain every K-step) to the 256-square 8-wave double-buffered
//     counted-vmcnt schedule (T3+T4+T5):
//       - BM=BN=256, BK=64, 512 thr = 8 waves (2Mx4N), 128x64 out per wave
//       - LDS 128 KiB: 2 buffers x (A 256x64 + B 256x64) bf16, chunk-XOR
//         swizzled (phys chunk = logical ^ (row&7)) -- conflict-free b128
//       - 4 phases per K-tile: {stage-next || ds_read subtile || 16 MFMA
//         with setprio}, raw s_barrier, ONE counted s_waitcnt vmcnt(4) per
//         K-tile (next-tile A stages issued before the wait => never 0)
//     prep kernel (gather W rows -> bf16, x -> bf16) unchanged.
// ---------------------------------------------------------------------------

typedef __bf16 bf16x8 __attribute__((ext_vector_type(8)));
typedef float f32x4 __attribute__((ext_vector_type(4)));

#define BM 256
#define BN 256
#define BK 64

__device__ __forceinline__ ushort f2bf(float f) {
  union { float f; uint32_t u; } c; c.f = f;
  uint32_t u = c.u;
  return (ushort)((u + 0x7FFFu + ((u >> 16) & 1u)) >> 16);
}

// blocks [0, S/8): gather 8 W rows -> bf16 + bias gather
// blocks [S/8, S/8 + N*D/1024): convert x -> bf16
__global__ __launch_bounds__(256) void prep_kernel(
    const float* __restrict__ x, const float* __restrict__ W,
    const float* __restrict__ bias, const int* __restrict__ ids,
    ushort* __restrict__ Wg, ushort* __restrict__ xb,
    float* __restrict__ biasg, int D, int S) {
  const int t = threadIdx.x;
  const int gblocks = S >> 3;
  if ((int)blockIdx.x < gblocks) {
    const int s0 = blockIdx.x << 3;
    if (t < 8) biasg[s0 + t] = bias[ids[s0 + t]];
#pragma unroll
    for (int r = 0; r < 8; ++r) {
      const int s = s0 + r;
      const int id = ids[s];
      float4 v = ((const float4*)(W + (size_t)id * D))[t];
      ushort4 o;
      o.x = f2bf(v.x); o.y = f2bf(v.y); o.z = f2bf(v.z); o.w = f2bf(v.w);
      ((ushort4*)(Wg + (size_t)s * D))[t] = o;
    }
  } else {
    const int i = (blockIdx.x - gblocks) * 256 + t;
    float4 v = ((const float4*)x)[i];
    ushort4 o;
    o.x = f2bf(v.x); o.y = f2bf(v.y); o.z = f2bf(v.z); o.w = f2bf(v.w);
    ((ushort4*)xb)[i] = o;
  }
}

__device__ __forceinline__ void load_lds16(const void* g, void* l) {
  __builtin_amdgcn_global_load_lds(
      (const __attribute__((address_space(1))) void*)g,
      (__attribute__((address_space(3))) void*)l, 16, 0, 0);
}

// C[M,S] = A[M,K](bf16) * B[S,K](bf16)^T + biasg[S], fp32 out.
// 512 thr = 8 waves (2x4 of 128x64), each wave 8x4 of 16x16x32 MFMA frags.
__global__ __launch_bounds__(512, 2) void gemm_bt_bias(
    const ushort* __restrict__ A, const ushort* __restrict__ B,
    const float* __restrict__ biasg, float* __restrict__ C,
    int M, int S, int K) {
  // [2 buf][256 rows][64 cols]; phys chunk p at row r holds logical p^(r&7)
  __shared__ __align__(16) ushort As[2 * BM * BK];
  __shared__ __align__(16) ushort Bs[2 * BN * BK];

  const int tid  = threadIdx.x;
  const int lane = tid & 63;
  const int wave = tid >> 6;
  const int wm = (wave >> 2) * 128;  // 0 / 128
  const int wn = (wave & 3) * 64;    // 0 / 64 / 128 / 192
  const int quad = lane >> 4;
  const int l16  = lane & 15;
  const int bn = blockIdx.x;
  const int bm = blockIdx.y;

  // staging: load j of thread tid -> LDS slot (j*512+tid)*16B
  //   == row (j*64 + tid/8), phys chunk tid%8; logical col = (phys^(row&7))*8
  const int srow = tid >> 3;                       // 0..63
  const int scol = (((tid & 7) ^ (srow & 7)) << 3);
  const ushort* Asrc = A + (size_t)(bm * BM + srow) * K + scol;
  const ushort* Bsrc = B + (size_t)(bn * BN + srow) * K + scol;

  // fragment read offsets: logical chunk = ks*4 + quad, row&7 == l16&7
  const int pc0 = ((quad ^ (l16 & 7)) << 3);        // ks=0 phys-chunk bytes/2
  const int pc1 = (((4 + quad) ^ (l16 & 7)) << 3);  // ks=1

  f32x4 acc[8][4] = {};

  auto stage_tile = [&](const ushort* src, ushort* dst, int kt) {
#pragma unroll
    for (int j = 0; j < 4; ++j)
      load_lds16(src + (size_t)(j * 64) * K + kt, dst + (j * 512 + tid) * 8);
  };

  auto load_af = [&](const ushort* Acur, int ih, bf16x8 (&af)[4][2]) {
#pragma unroll
    for (int i = 0; i < 4; ++i) {
      const int ro = (wm + (ih * 4 + i) * 16 + l16) * BK;
      af[i][0] = *(const bf16x8*)(Acur + ro + pc0);
      af[i][1] = *(const bf16x8*)(Acur + ro + pc1);
    }
  };
  auto load_bq = [&](const ushort* Bcur, int jh, bf16x8 (&bq)[2][2]) {
#pragma unroll
    for (int j = 0; j < 2; ++j) {
      const int ro = (wn + (jh * 2 + j) * 16 + l16) * BK;
      bq[j][0] = *(const bf16x8*)(Bcur + ro + pc0);
      bq[j][1] = *(const bf16x8*)(Bcur + ro + pc1);
    }
  };
  auto mma_q = [&](bf16x8 (&af)[4][2], bf16x8 (&bq)[2][2], int ih, int jh) {
    __builtin_amdgcn_s_setprio(1);
#pragma unroll
    for (int ks = 0; ks < 2; ++ks)
#pragma unroll
      for (int i = 0; i < 4; ++i)
#pragma unroll
        for (int j = 0; j < 2; ++j)
          acc[ih * 4 + i][jh * 2 + j] =
              __builtin_amdgcn_mfma_f32_16x16x32_bf16(
                  af[i][ks], bq[j][ks], acc[ih * 4 + i][jh * 2 + j], 0, 0, 0);
    __builtin_amdgcn_s_setprio(0);
  };

  // prologue: stage K-tile 0 into buffer 0 (8 loads in flight)
  stage_tile(Asrc, (ushort*)As, 0);
  stage_tile(Bsrc, (ushort*)Bs, 0);

  const int NT = K / BK;
  for (int t = 0; t < NT; ++t) {
    const int cur = t & 1;
    const ushort* Acur = (const ushort*)As + cur * (BM * BK);
    const ushort* Bcur = (const ushort*)Bs + cur * (BN * BK);
    ushort* Anx = (ushort*)As + (cur ^ 1) * (BM * BK);
    ushort* Bnx = (ushort*)Bs + (cur ^ 1) * (BN * BK);
    const int kn = (t + 1) * BK;

    // -- phase 0: issue next-A stages, counted wait (retires all 8 loads of
    //    tile t in every wave), barrier -> buf[cur] visible; quad (0,0)
    if (t + 1 < NT) {
      stage_tile(Asrc, Anx, kn);
      asm volatile("s_waitcnt vmcnt(4)" ::: "memory");
    } else {
      asm volatile("s_waitcnt vmcnt(0)" ::: "memory");  // drain once, at tail
    }
    __builtin_amdgcn_sched_barrier(0);
    __builtin_amdgcn_s_barrier();
    __builtin_amdgcn_sched_barrier(0);

    bf16x8 af[4][2], bq0[2][2], bq1[2][2];
    load_af(Acur, 0, af);
    load_bq(Bcur, 0, bq0);
    mma_q(af, bq0, 0, 0);

    // -- phase 1: issue next-B stages; quad (0,1)
    if (t + 1 < NT) stage_tile(Bsrc, Bnx, kn);
    load_bq(Bcur, 1, bq1);
    mma_q(af, bq1, 0, 1);

    // -- phase 2: quad (1,1)
    load_af(Acur, 1, af);
    mma_q(af, bq1, 1, 1);

    // -- phase 3: quad (1,0) (re-read B half 0: keeps VGPR < 256, no spill)
    load_bq(Bcur, 0, bq0);
    mma_q(af, bq0, 1, 0);

    // end-of-tile barrier: all waves' ds_reads of buf[cur] done before the
    // next tile's stages (which write buf[cur]) can land
    __builtin_amdgcn_sched_barrier(0);
    __builtin_amdgcn_s_barrier();
    __builtin_amdgcn_sched_barrier(0);
  }

  // epilogue: C/D layout col = lane&15, row = quad*4 + reg  [m89/m91]
  const int row0 = bm * BM + wm + quad * 4;
  const int col0 = bn * BN + wn + l16;
#pragma unroll
  for (int jf = 0; jf < 4; ++jf) {
    const int col = col0 + jf * 16;
    const float bv = biasg[col];
#pragma unroll
    for (int i = 0; i < 8; ++i) {
#pragma unroll
      for (int r = 0; r < 4; ++r) {
        C[(size_t)(row0 + i * 16 + r) * S + col] = acc[i][jf][r] + bv;
      }
    }
  }
}

extern "C" void kernel_launch(void* const* d_in, const int* in_sizes, int n_in,
                              void* d_out, int out_size, void* d_ws, size_t ws_size,
                              hipStream_t stream) {
  const float* x    = (const float*)d_in[0];  // [N, D]
  const float* W    = (const float*)d_in[1];  // [OUT, D]
  const float* bias = (const float*)d_in[2];  // [OUT]
  const int*   ids  = (const int*)d_in[3];    // [S]
  float* out = (float*)d_out;                 // [N, S]

  const int OUTN = in_sizes[2];
  const int S    = in_sizes[3];
  const int D    = in_sizes[1] / OUTN;  // 1024
  const int N    = in_sizes[0] / D;     // 2048

  // workspace: Wg bf16 [S,D] | xb bf16 [N,D] | biasg f32 [S]
  ushort* Wg = (ushort*)d_ws;
  ushort* xb = (ushort*)((char*)d_ws + (size_t)S * D * sizeof(ushort));
  float* biasg = (float*)((char*)d_ws + (size_t)S * D * sizeof(ushort)
                          + (size_t)N * D * sizeof(ushort));

  const int gather_blocks = S / 8;
  const int conv_blocks = (N * D) / 1024;  // 256 thr * 4 floats
  prep_kernel<<<gather_blocks + conv_blocks, 256, 0, stream>>>(
      x, W, bias, ids, Wg, xb, biasg, D, S);

  dim3 grid(S / BN, N / BM);  // 64 x 8 = 512 blocks, 1 block/CU (128 KiB LDS)
  gemm_bt_bias<<<grid, 512, 0, stream>>>(xb, Wg, biasg, out, N, S, D);
}

// Round 2
// 437.327 us; speedup vs baseline: 1.0300x; 1.0300x over previous
//
#include <hip/hip_runtime.h>
#include <stdint.h>

// ---------------------------------------------------------------------------
// LSH layer: out[n,s] = sum_d x[n,d] * W[ids[s],d] + bias[ids[s]]
// R4: faithful m201-style 8-phase schedule (T2+T3+T4+T5), race-free by
//     construction:
//       - BM=BN=256, BK=64, 512 thr = 8 waves (2Mx4N), 128x64 out/wave
//       - staging granularity = K-half (256x32, 2 gload_lds/thread);
//         per tile: {A-k0, A-k1, B-k0, B-k1} -> 4 half-buffers/dbuf
//       - 4 phases/tile: ph0 {rd a_lo+b (k0), stage A-k0(t+1)},
//         ph1 {rd a_hi (k0), stage B-k0(t+1), vmcnt(4)},
//         ph2 {rd a_lo+b (k1), stage A-k1(t+1)},
//         ph3 {rd a_hi (k1), stage B-k1(t+1), vmcnt(4)}
//         each phase: reads/stage -> barrier -> lgkmcnt(0) -> setprio(1) ->
//         16 MFMA -> setprio(0) -> barrier  (vmcnt before closing barrier)
//       - FIFO-verified: vmcnt(4) at ph1/ph3 retires exactly the half-tiles
//         the next two phases read; 2-4 half-tiles always in flight
//       - LDS swizzle for [256][32] half: phys chunk = logical ^ ((row>>1)&3)
//         (conflict-free b128 reads; per-thread constant)
//       - bijective XCD swizzle (512 blocks % 8 == 0)
// ---------------------------------------------------------------------------

typedef __bf16 bf16x8 __attribute__((ext_vector_type(8)));
typedef float f32x4 __attribute__((ext_vector_type(4)));

#define BM 256
#define BN 256
#define BK 64
#define KH 32
#define HB 8192  // ushorts per half-buffer: 256*32

__device__ __forceinline__ ushort f2bf(float f) {
  union { float f; uint32_t u; } c; c.f = f;
  uint32_t u = c.u;
  return (ushort)((u + 0x7FFFu + ((u >> 16) & 1u)) >> 16);
}

__global__ __launch_bounds__(256) void prep_kernel(
    const float* __restrict__ x, const float* __restrict__ W,
    const float* __restrict__ bias, const int* __restrict__ ids,
    ushort* __restrict__ Wg, ushort* __restrict__ xb,
    float* __restrict__ biasg, int D, int S) {
  const int t = threadIdx.x;
  const int gblocks = S >> 3;
  if ((int)blockIdx.x < gblocks) {
    const int s0 = blockIdx.x << 3;
    if (t < 8) biasg[s0 + t] = bias[ids[s0 + t]];
#pragma unroll
    for (int r = 0; r < 8; ++r) {
      const int s = s0 + r;
      const int id = ids[s];
      float4 v = ((const float4*)(W + (size_t)id * D))[t];
      ushort4 o;
      o.x = f2bf(v.x); o.y = f2bf(v.y); o.z = f2bf(v.z); o.w = f2bf(v.w);
      ((ushort4*)(Wg + (size_t)s * D))[t] = o;
    }
  } else {
    const int i = (blockIdx.x - gblocks) * 256 + t;
    float4 v = ((const float4*)x)[i];
    ushort4 o;
    o.x = f2bf(v.x); o.y = f2bf(v.y); o.z = f2bf(v.z); o.w = f2bf(v.w);
    ((ushort4*)xb)[i] = o;
  }
}

__device__ __forceinline__ void load_lds16(const void* g, void* l) {
  __builtin_amdgcn_global_load_lds(
      (const __attribute__((address_space(1))) void*)g,
      (__attribute__((address_space(3))) void*)l, 16, 0, 0);
}

#define OPEN_BAR()                                        \
  do {                                                    \
    __builtin_amdgcn_sched_barrier(0);                    \
    __builtin_amdgcn_s_barrier();                         \
    asm volatile("s_waitcnt lgkmcnt(0)" ::: "memory");    \
    __builtin_amdgcn_sched_barrier(0);                    \
  } while (0)
#define CLOSE_BAR()                                       \
  do {                                                    \
    __builtin_amdgcn_sched_barrier(0);                    \
    __builtin_amdgcn_s_barrier();                         \
    __builtin_amdgcn_sched_barrier(0);                    \
  } while (0)

// C[M,S] = A[M,K](bf16) * B[S,K](bf16)^T + biasg[S], fp32 out.
__global__ __launch_bounds__(512, 2) void gemm_bt_bias(
    const ushort* __restrict__ A, const ushort* __restrict__ B,
    const float* __restrict__ biasg, float* __restrict__ C,
    int M, int S, int K) {
  // [dbuf(2)][khalf(2)][256 rows][32 cols], phys chunk = logical^((row>>1)&3)
  __shared__ __align__(16) ushort As[4 * HB];
  __shared__ __align__(16) ushort Bs[4 * HB];

  const int tid  = threadIdx.x;
  const int lane = tid & 63;
  const int wave = tid >> 6;
  const int wm = (wave >> 2) * 128;
  const int wn = (wave & 3) * 64;
  const int quad = lane >> 4;
  const int l16  = lane & 15;

  // bijective XCD swizzle of flattened block id (nwg = 512, %8 == 0)
  const int gx = gridDim.x;
  int id = blockIdx.y * gx + blockIdx.x;
  const int cpx = (gx * gridDim.y) >> 3;
  id = (id & 7) * cpx + (id >> 3);
  const int bn = id % gx;
  const int bm = id / gx;

  // staging: thread tid, load j -> LDS slot (j*512+tid)*16B within half-buf
  //   row = j*128 + tid/4, phys chunk = tid&3, logical = phys ^ ((row>>1)&3)
  const int srow = tid >> 2;  // + j*128 (swizzle bits unchanged: +64 on row>>1)
  const int scol = (((tid & 3) ^ ((srow >> 1) & 3)) << 3);
  const ushort* Asrc = A + (size_t)(bm * BM + srow) * K + scol;
  const ushort* Bsrc = B + (size_t)(bn * BN + srow) * K + scol;

  // frag reads: row = w*+i*16+l16 -> (row>>1)&3 == (l16>>1)&3 (per-thread const)
  const int rchunk = ((quad ^ ((l16 >> 1) & 3)) << 3);

  f32x4 acc[8][4] = {};

  auto stageA = [&](int hb, int t, int h) {
#pragma unroll
    for (int j = 0; j < 2; ++j)
      load_lds16(Asrc + (size_t)(j * 128) * K + t * BK + h * KH,
                 As + hb * HB + (j * 512 + tid) * 8);
  };
  auto stageB = [&](int hb, int t, int h) {
#pragma unroll
    for (int j = 0; j < 2; ++j)
      load_lds16(Bsrc + (size_t)(j * 128) * K + t * BK + h * KH,
                 Bs + hb * HB + (j * 512 + tid) * 8);
  };
  auto rdA = [&](bf16x8 (&a)[4], int hb, int ibase) {
#pragma unroll
    for (int i = 0; i < 4; ++i)
      a[i] = *(const bf16x8*)(As + hb * HB +
                              (wm + (ibase + i) * 16 + l16) * KH + rchunk);
  };
  auto rdB = [&](bf16x8 (&b)[4], int hb) {
#pragma unroll
    for (int j = 0; j < 4; ++j)
      b[j] = *(const bf16x8*)(Bs + hb * HB + (wn + j * 16 + l16) * KH + rchunk);
  };
  auto mma16 = [&](bf16x8 (&a)[4], bf16x8 (&b)[4], int ibase) {
    __builtin_amdgcn_s_setprio(1);
#pragma unroll
    for (int i = 0; i < 4; ++i)
#pragma unroll
      for (int j = 0; j < 4; ++j)
        acc[ibase + i][j] = __builtin_amdgcn_mfma_f32_16x16x32_bf16(
            a[i], b[j], acc[ibase + i][j], 0, 0, 0);
    __builtin_amdgcn_s_setprio(0);
  };

  // prologue: stage tile 0 in order A0,B0,A1,B1; retire A0,B0; barrier
  stageA(0, 0, 0); stageB(0, 0, 0); stageA(1, 0, 1); stageB(1, 0, 1);
  __builtin_amdgcn_sched_barrier(0);
  asm volatile("s_waitcnt vmcnt(4)" ::: "memory");
  __builtin_amdgcn_s_barrier();
  __builtin_amdgcn_sched_barrier(0);

  const int NT = K / BK;
  bf16x8 alo[4], ahi[4], bb[4];

  for (int t = 0; t < NT - 1; ++t) {
    const int d  = (t & 1) * 2;
    const int dn = 2 - d;

    // phase 0: k0 | i0-3 ; stage A-k0(t+1)
    rdA(alo, d + 0, 0);
    rdB(bb,  d + 0);
    stageA(dn + 0, t + 1, 0);
    OPEN_BAR();
    mma16(alo, bb, 0);
    CLOSE_BAR();

    // phase 1: k0 | i4-7 ; stage B-k0(t+1); retire A-k1(t),B-k1(t)
    rdA(ahi, d + 0, 4);
    stageB(dn + 0, t + 1, 0);
    OPEN_BAR();
    mma16(ahi, bb, 4);
    __builtin_amdgcn_sched_barrier(0);
    asm volatile("s_waitcnt vmcnt(4)" ::: "memory");
    CLOSE_BAR();

    // phase 2: k1 | i0-3 ; stage A-k1(t+1)
    rdA(alo, d + 1, 0);
    rdB(bb,  d + 1);
    stageA(dn + 1, t + 1, 1);
    OPEN_BAR();
    mma16(alo, bb, 0);
    CLOSE_BAR();

    // phase 3: k1 | i4-7 ; stage B-k1(t+1); retire A-k0(t+1),B-k0(t+1)
    rdA(ahi, d + 1, 4);
    stageB(dn + 1, t + 1, 1);
    OPEN_BAR();
    mma16(ahi, bb, 4);
    __builtin_amdgcn_sched_barrier(0);
    asm volatile("s_waitcnt vmcnt(4)" ::: "memory");
    CLOSE_BAR();
  }

  // tail tile (no staging): entry in-flight = [A-k1, B-k1] of this tile
  {
    const int d = ((NT - 1) & 1) * 2;

    rdA(alo, d + 0, 0);
    rdB(bb,  d + 0);
    OPEN_BAR();
    mma16(alo, bb, 0);
    CLOSE_BAR();

    rdA(ahi, d + 0, 4);
    OPEN_BAR();
    mma16(ahi, bb, 4);
    __builtin_amdgcn_sched_barrier(0);
    asm volatile("s_waitcnt vmcnt(0)" ::: "memory");
    CLOSE_BAR();

    rdA(alo, d + 1, 0);
    rdB(bb,  d + 1);
    OPEN_BAR();
    mma16(alo, bb, 0);
    CLOSE_BAR();

    rdA(ahi, d + 1, 4);
    OPEN_BAR();
    mma16(ahi, bb, 4);
    __builtin_amdgcn_sched_barrier(0);
  }

  // epilogue: C/D layout col = lane&15, row = quad*4 + reg  [m89/m91]
  const int row0 = bm * BM + wm + quad * 4;
  const int col0 = bn * BN + wn + l16;
#pragma unroll
  for (int jf = 0; jf < 4; ++jf) {
    const int col = col0 + jf * 16;
    const float bv = biasg[col];
#pragma unroll
    for (int i = 0; i < 8; ++i) {
#pragma unroll
      for (int r = 0; r < 4; ++r) {
        C[(size_t)(row0 + i * 16 + r) * S + col] = acc[i][jf][r] + bv;
      }
    }
  }
}

extern "C" void kernel_launch(void* const* d_in, const int* in_sizes, int n_in,
                              void* d_out, int out_size, void* d_ws, size_t ws_size,
                              hipStream_t stream) {
  const float* x    = (const float*)d_in[0];  // [N, D]
  const float* W    = (const float*)d_in[1];  // [OUT, D]
  const float* bias = (const float*)d_in[2];  // [OUT]
  const int*   ids  = (const int*)d_in[3];    // [S]
  float* out = (float*)d_out;                 // [N, S]

  const int OUTN = in_sizes[2];
  const int S    = in_sizes[3];
  const int D    = in_sizes[1] / OUTN;  // 1024
  const int N    = in_sizes[0] / D;     // 2048

  // workspace: Wg bf16 [S,D] | xb bf16 [N,D] | biasg f32 [S]
  ushort* Wg = (ushort*)d_ws;
  ushort* xb = (ushort*)((char*)d_ws + (size_t)S * D * sizeof(ushort));
  float* biasg = (float*)((char*)d_ws + (size_t)S * D * sizeof(ushort)
                          + (size_t)N * D * sizeof(ushort));

  const int gather_blocks = S / 8;
  const int conv_blocks = (N * D) / 1024;
  prep_kernel<<<gather_blocks + conv_blocks, 256, 0, stream>>>(
      x, W, bias, ids, Wg, xb, biasg, D, S);

  dim3 grid(S / BN, N / BM);  // 64 x 8 = 512 blocks
  gemm_bt_bias<<<grid, 512, 0, stream>>>(xb, Wg, biasg, out, N, S, D);
}